// Round 4
// baseline (471.952 us; speedup 1.0000x reference)
//
#include <hip/hip_runtime.h>
#include <cstdint>
#include <cstdio>

#define DEVI __device__ __forceinline__

constexpr int TOKS = 8192;
constexpr int HID  = 1024;
constexpr int INTR = 2048;
constexpr int SINT = 1024;
constexpr int NEXP = 8;
constexpr int MAXSLOT = 17408;   // 16384 assignments + 8*127 padding, rounded up

typedef __bf16 bf16x8 __attribute__((ext_vector_type(8)));
typedef float  f32x4  __attribute__((ext_vector_type(4)));

DEVI unsigned short f2bf(float f) {
  unsigned int u = __float_as_uint(f);
  u += 0x7FFFu + ((u >> 16) & 1u);   // round-to-nearest-even
  return (unsigned short)(u >> 16);
}

DEVI float bf2f(unsigned short h) {
  return __uint_as_float((unsigned int)h << 16);
}

// async global->LDS, 16B per lane. LDS dest = wave-uniform base + lane*16
// (our per-thread tid*16B dest is exactly that); global addr per-lane (gather OK).
DEVI void gl_lds16(const unsigned short* g, unsigned short* l) {
  __attribute__((address_space(1))) uint32_t* gp =
      (__attribute__((address_space(1))) uint32_t*)(uintptr_t)g;
  __attribute__((address_space(3))) uint32_t* lp =
      (__attribute__((address_space(3))) uint32_t*)(uint32_t)(uintptr_t)l;
  __builtin_amdgcn_global_load_lds(gp, lp, 16, 0, 0);
}

// exact-gelu via Abramowitz-Stegun 7.1.26 erf (|err| <= 1.5e-7), ~14 VALU ops.
DEVI float gelu_fast(float x) {
  const float z = fabsf(x) * 0.70710678118654752f;
  const float t = __builtin_amdgcn_rcpf(1.0f + 0.3275911f * z);
  float p = 1.061405429f;
  p = p * t - 1.453152027f;
  p = p * t + 1.421413741f;
  p = p * t - 0.284496736f;
  p = p * t + 0.254829592f;
  const float e = __builtin_amdgcn_exp2f(-z * z * 1.4426950408889634f);  // exp(-z^2)
  float erfz = 1.0f - p * t * e;     // erf(|z|)
  erfz = copysignf(erfz, x);
  return 0.5f * x * (1.0f + erfz);
}

// bijective XCD-chunked remap (m204): XCD k (= bid%8 dispatch heuristic) owns a
// contiguous chunk of the active tile space -> per-XCD L2 keeps one B-panel hot.
DEVI int xcd_chunk_map(int bid, int total) {
  const int q = total >> 3, r = total & 7;
  const int x = bid & 7, i = bid >> 3;
  return (x < r ? x * (q + 1) : r * (q + 1) + (x - r) * q) + i;
}

// ---------------- fused fp32 -> bf16 convert over 4 weight arrays ----------------
__global__ void k_f2bf_all(const float* __restrict__ s0, unsigned short* __restrict__ d0, int n0,
                           const float* __restrict__ s1, unsigned short* __restrict__ d1, int n1,
                           const float* __restrict__ s2, unsigned short* __restrict__ d2, int n2,
                           const float* __restrict__ s3, unsigned short* __restrict__ d3, int n3) {
  const int ntot = n0 + n1 + n2 + n3;
  int i = blockIdx.x * blockDim.x + threadIdx.x;
  const int stride = gridDim.x * blockDim.x;
  for (; i < ntot; i += stride) {
    int j = i;
    const float* s; unsigned short* d;
    if (j < n0) { s = s0; d = d0; }
    else if ((j -= n0) < n1) { s = s1; d = d1; }
    else if ((j -= n1) < n2) { s = s2; d = d2; }
    else { j -= n2; s = s3; d = d3; }
    float4 v = ((const float4*)s)[j];
    ushort4 o;
    o.x = f2bf(v.x); o.y = f2bf(v.y); o.z = f2bf(v.z); o.w = f2bf(v.w);
    ((ushort4*)d)[j] = o;
  }
}

// ---------------- router: fp32 logits, top-2, softmax. NO ATOMICS. ----------------
__global__ __launch_bounds__(256) void k_router(
    const float* __restrict__ x, const float* __restrict__ wg,
    unsigned short* __restrict__ xb,
    int* __restrict__ rec_e, float2* __restrict__ rec_g) {
  const int wave = threadIdx.x >> 6;
  const int lane = threadIdx.x & 63;
  const int t = blockIdx.x * 4 + wave;

  float4 xv[4];
  const float4* x4 = (const float4*)(x + (size_t)t * HID);
#pragma unroll
  for (int j = 0; j < 4; ++j) xv[j] = x4[j * 64 + lane];

  // emit bf16 copy of x
  ushort4* xb4 = (ushort4*)(xb + (size_t)t * HID);
#pragma unroll
  for (int j = 0; j < 4; ++j) {
    float4 v = xv[j];
    ushort4 o; o.x = f2bf(v.x); o.y = f2bf(v.y); o.z = f2bf(v.z); o.w = f2bf(v.w);
    xb4[j * 64 + lane] = o;
  }

  float lg[NEXP];
#pragma unroll
  for (int e = 0; e < NEXP; ++e) {
    const float4* w4 = (const float4*)(wg + (size_t)e * HID);
    float s = 0.f;
#pragma unroll
    for (int j = 0; j < 4; ++j) {
      float4 a = xv[j], b = w4[j * 64 + lane];
      s += a.x * b.x + a.y * b.y + a.z * b.z + a.w * b.w;
    }
    lg[e] = s;
  }
#pragma unroll
  for (int e = 0; e < NEXP; ++e)
#pragma unroll
    for (int off = 32; off > 0; off >>= 1) lg[e] += __shfl_xor(lg[e], off);

  if (lane == 0) {
    int b0 = 0; float v0 = lg[0];
    for (int e = 1; e < NEXP; ++e) if (lg[e] > v0) { v0 = lg[e]; b0 = e; }
    int b1 = -1; float v1 = -1e30f;
    for (int e = 0; e < NEXP; ++e) if (e != b0 && lg[e] > v1) { v1 = lg[e]; b1 = e; }
    const float d = expf(v1 - v0);
    const float g0 = 1.f / (1.f + d);
    const float g1 = d / (1.f + d);
    rec_e[t] = b0 | (b1 << 16);
    rec_g[t] = make_float2(g0, g1);
  }
}

// ---------------- count: hierarchical rank-within-expert (LDS hist + 8 global atomics/block) ----------------
__global__ __launch_bounds__(256) void k_count(
    const int* __restrict__ rec_e, int* __restrict__ rec_p, int* __restrict__ cnt) {
  __shared__ int hist[NEXP];
  __shared__ int base[NEXP];
  const int t = blockIdx.x * 256 + threadIdx.x;
  if (threadIdx.x < NEXP) hist[threadIdx.x] = 0;
  __syncthreads();
  const int ee = rec_e[t];
  const int e0 = ee & 0xffff, e1 = ee >> 16;
  const int r0 = atomicAdd(&hist[e0], 1);   // LDS atomic: intra-block rank
  const int r1 = atomicAdd(&hist[e1], 1);
  __syncthreads();
  if (threadIdx.x < NEXP)
    base[threadIdx.x] = atomicAdd(&cnt[threadIdx.x], hist[threadIdx.x]);  // 8 global atomics/block
  __syncthreads();
  rec_p[t] = (base[e0] + r0) | ((base[e1] + r1) << 16);
}

// ---------------- scan: 128-padded offsets + per-expert tile tables ----------------
// offs[0..8]  : 128-padded slot offsets
// offs[16..24]: tb0 cumulative tile count for expert-fc   (m-tiles * INTR/128)
// offs[32..40]: tb1 cumulative tile count for expert-proj (m-tiles * HID/128)
__global__ void k_scan(const int* __restrict__ cnt, int* __restrict__ offs) {
  if (threadIdx.x == 0 && blockIdx.x == 0) {
    int* tb0 = offs + 16;
    int* tb1 = offs + 32;
    int o = 0, t0 = 0, t1 = 0;
    tb0[0] = 0; tb1[0] = 0;
    for (int e = 0; e < NEXP; ++e) {
      offs[e] = o;
      const int mt = (cnt[e] + 127) >> 7;
      o += mt << 7;
      t0 += mt * (INTR / 128);
      t1 += mt * (HID / 128);
      tb0[e + 1] = t0;
      tb1[e + 1] = t1;
    }
    offs[NEXP] = o;
  }
}

// ---------------- assign: fill slot arrays ----------------
__global__ void k_assign(const int* __restrict__ rec_e, const int* __restrict__ rec_p,
                         const int* __restrict__ offs, int* __restrict__ tok) {
  const int t = blockIdx.x * 256 + threadIdx.x;
  if (t >= TOKS) return;
  const int ee = rec_e[t], pp = rec_p[t];
  const int s0 = offs[ee & 0xffff] + (pp & 0xffff);
  const int s1 = offs[ee >> 16] + (pp >> 16);
  tok[s0] = t;
  tok[s1] = t;
}

// ---------------- GEMM: C[m,n] = sum_k A[m,k]*B[n,k]  (B row-major [N,K]) ----------------
// 128x128 tile, 256 thr = 4 waves (2Mx2N). T3/T4: 4-buffer BK=32 depth-3 pipeline with
// COUNTED vmcnt (never 0 in main loop): prologue stages tiles 0..2; iter t waits
// vmcnt(8) (tile t's 4 loads/thread landed; t+1,t+2 stay in flight ACROSS the barrier),
// raw s_barrier (no drain), ds_read 8 frags, stage(t+3), 16 MFMA. LDS 4x16KB = 64KB
// -> 2 blocks/CU. Swizzle for 64B rows: chunk ^ ((row>>1)&3) — 8 rows cover all 8
// bank granules (2 lanes/bank = free, same minimum as r3's verified 0-conflict layout),
// applied on BOTH staging source and ds_read addr (rule 21).
// Buffer liveness mod 4: {read t, staged t+1, t+2, write t+3 == t-1's buffer}, stage(t+3)
// separated from iter t-1's reads by barrier(t). Tail iters wait vmcnt(4)/vmcnt(0).
// MODE 0: expert fc (gather via tok[], gelu)  MODE 1: expert proj (raw)
// MODE 2: shared fc (gelu)                    MODE 3: shared proj (raw)
template <int MODE>
__global__ __launch_bounds__(256, 2) void k_gemm2(
    const unsigned short* __restrict__ A,
    const unsigned short* __restrict__ B,
    unsigned short* __restrict__ Hout,
    const int* __restrict__ cnt,
    const int* __restrict__ offs,
    const int* __restrict__ tok,
    int K, int N) {
  constexpr int NT_SHIFT = (MODE == 0) ? 4 : 3;   // log2(N/128)
  constexpr int NT_TILES = 1 << NT_SHIFT;

  int count, off, e = 0, m0, n0;
  {
    int bid = blockIdx.x;
    int total;
    const int* tb = offs + ((MODE == 0) ? 16 : 32);
    if constexpr (MODE <= 1) total = tb[8];
    else                     total = (TOKS >> 7) << NT_SHIFT;
    if (bid >= total) return;                 // tail overflow blocks exit fast
    bid = xcd_chunk_map(bid, total);
    int local;
    if constexpr (MODE <= 1) {
      while (bid >= tb[e + 1]) ++e;           // <=8 scalar iters
      local = bid - tb[e];
      count = cnt[e]; off = offs[e];
    } else {
      local = bid; count = TOKS; off = 0;
    }
    m0 = (local >> NT_SHIFT) << 7;            // nt-fastest: chunk covers all N of one m-tile
    n0 = (local & (NT_TILES - 1)) << 7;
  }

  __shared__ alignas(16) unsigned short As[4][128 * 32];   // 4 x 8KB
  __shared__ alignas(16) unsigned short Bs[4][128 * 32];   // 4 x 8KB  (64KB total)

  const int tid = threadIdx.x;
  const unsigned short* Bexp = B + ((MODE <= 1) ? (size_t)e * N * K : (size_t)0);

  // ---- staging: 2 rounds of 64 rows each (256 thr x 16B = 4KB/round); source chunk
  // pre-swizzled (chunk ^ ((row>>1)&3)), LDS dest lane-linear ----
  const int srow = tid >> 2;                  // 0..63
  const int schunk = tid & 3;                 // 16B chunk within 64B row
  const unsigned short* gA[2];
  const unsigned short* gB[2];
#pragma unroll
  for (int r = 0; r < 2; ++r) {
    const int gr = r * 64 + srow;             // row within tile (0..127)
    int mr = m0 + gr; if (mr > count - 1) mr = count - 1;   // clamp tail rows
    size_t arow;
    if (MODE == 0)      arow = (size_t)tok[off + mr] * (size_t)K;
    else if (MODE == 1) arow = (size_t)(off + mr) * (size_t)K;
    else                arow = (size_t)(m0 + gr) * (size_t)K;
    const int sc = (schunk ^ ((gr >> 1) & 3)) * 8;
    gA[r] = A + arow + (size_t)sc;
    gB[r] = Bexp + (size_t)(n0 + gr) * (size_t)K + (size_t)sc;
  }

  // ---- ds_read byte offsets (swizzled) ----
  const int wid = tid >> 6;
  const int lane = tid & 63;
  const int wr = wid >> 1;                    // 0..1
  const int wc = wid & 1;                     // 0..1
  const int fm = lane & 15;
  const int fq = lane >> 4;
  int aOff[4], bOff[4];
#pragma unroll
  for (int i = 0; i < 4; ++i) {
    const int row = wr * 64 + i * 16 + fm;
    aOff[i] = row * 64 + ((fq ^ ((row >> 1) & 3)) * 16);
  }
#pragma unroll
  for (int j = 0; j < 4; ++j) {
    const int row = wc * 64 + j * 16 + fm;
    bOff[j] = row * 64 + ((fq ^ ((row >> 1) & 3)) * 16);
  }

  auto stage = [&](int buf, int k0) {         // k0 in shorts; 4 loads/thread
    gl_lds16(gA[0] + k0, &As[buf][tid * 8]);
    gl_lds16(gA[1] + k0, &As[buf][2048 + tid * 8]);
    gl_lds16(gB[0] + k0, &Bs[buf][tid * 8]);
    gl_lds16(gB[1] + k0, &Bs[buf][2048 + tid * 8]);
  };

  f32x4 acc[4][4] = {};

  auto kstep = [&](int t, bool doStage) {
    const char* aB = (const char*)&As[t & 3][0];
    const char* bB = (const char*)&Bs[t & 3][0];
    bf16x8 af[4], bfr[4];
#pragma unroll
    for (int i = 0; i < 4; ++i) af[i] = *(const bf16x8*)(aB + aOff[i]);
#pragma unroll
    for (int j = 0; j < 4; ++j) bfr[j] = *(const bf16x8*)(bB + bOff[j]);
    if (doStage) stage((t + 3) & 3, (t + 3) * 32);
    __builtin_amdgcn_s_setprio(1);
#pragma unroll
    for (int i = 0; i < 4; ++i)
#pragma unroll
      for (int j = 0; j < 4; ++j)
        acc[i][j] = __builtin_amdgcn_mfma_f32_16x16x32_bf16(af[i], bfr[j], acc[i][j], 0, 0, 0);
    __builtin_amdgcn_s_setprio(0);
  };

  // prologue: 3 tiles in flight (12 loads/thread outstanding)
  stage(0, 0);
  stage(1, 32);
  stage(2, 64);

  const int NT = K >> 5;                      // 32 or 64 K-steps
  for (int t = 0; t < NT - 2; ++t) {
    asm volatile("s_waitcnt vmcnt(8)" ::: "memory");   // tile t landed; t+1,t+2 in flight
    __builtin_amdgcn_s_barrier();
    __builtin_amdgcn_sched_barrier(0);
    kstep(t, t + 3 < NT);
  }
  asm volatile("s_waitcnt vmcnt(4)" ::: "memory");     // tile NT-2 landed
  __builtin_amdgcn_s_barrier();
  __builtin_amdgcn_sched_barrier(0);
  kstep(NT - 2, false);
  asm volatile("s_waitcnt vmcnt(0)" ::: "memory");     // tile NT-1 landed
  __builtin_amdgcn_s_barrier();
  __builtin_amdgcn_sched_barrier(0);
  kstep(NT - 1, false);

  // ---- epilogue: C/D row = fq*4 + reg, col = lane&15 ----
  constexpr bool GELU = (MODE == 0 || MODE == 2);
#pragma unroll
  for (int i = 0; i < 4; ++i) {
#pragma unroll
    for (int rr = 0; rr < 4; ++rr) {
      const int m = m0 + wr * 64 + i * 16 + fq * 4 + rr;
      if (m < count) {                        // guard pad rows
        unsigned short* orow = Hout + (size_t)(off + m) * N + (n0 + wc * 64 + fm);
#pragma unroll
        for (int j = 0; j < 4; ++j) {
          const float v = acc[i][j][rr];
          orow[j * 16] = f2bf(GELU ? gelu_fast(v) : v);
        }
      }
    }
  }
}

// ---------------- combine: out[t] = g0*Y[s0] + g1*Y[s1] + Ys[t] ----------------
__global__ __launch_bounds__(256) void k_combine(
    const unsigned short* __restrict__ Y,   // [MAXSLOT, HID] bf16
    const unsigned short* __restrict__ Ys,  // [TOKS, HID] bf16
    const int* __restrict__ rec_e, const int* __restrict__ rec_p,
    const float2* __restrict__ rec_g, const int* __restrict__ offs,
    float* __restrict__ out) {
  const int t = blockIdx.x;
  const int ee = rec_e[t], pp = rec_p[t];
  const float2 g = rec_g[t];
  const int s0 = offs[ee & 0xffff] + (pp & 0xffff);
  const int s1 = offs[ee >> 16] + (pp >> 16);
  const int c = threadIdx.x * 4;
  ushort4 a = *(const ushort4*)&Y[(size_t)s0 * HID + c];
  ushort4 b = *(const ushort4*)&Y[(size_t)s1 * HID + c];
  ushort4 s = *(const ushort4*)&Ys[(size_t)t * HID + c];
  float4 o;
  o.x = g.x * bf2f(a.x) + g.y * bf2f(b.x) + bf2f(s.x);
  o.y = g.x * bf2f(a.y) + g.y * bf2f(b.y) + bf2f(s.y);
  o.z = g.x * bf2f(a.z) + g.y * bf2f(b.z) + bf2f(s.z);
  o.w = g.x * bf2f(a.w) + g.y * bf2f(b.w) + bf2f(s.w);
  *(float4*)&out[(size_t)t * HID + c] = o;
}

extern "C" void kernel_launch(void* const* d_in, const int* in_sizes, int n_in,
                              void* d_out, int out_size, void* d_ws, size_t ws_size,
                              hipStream_t stream) {
  const float* x   = (const float*)d_in[0];
  const float* wg  = (const float*)d_in[1];
  const float* wfc = (const float*)d_in[2];
  const float* wpj = (const float*)d_in[3];
  const float* wfs = (const float*)d_in[4];
  const float* wps = (const float*)d_in[5];
  float* out = (float*)d_out;
  char* ws = (char*)d_ws;

  // workspace layout (bytes)
  constexpr size_t OFF_XB   = 0;                                  // 16.78 MB
  constexpr size_t OFF_WFC  = OFF_XB   + (size_t)TOKS * HID * 2;  // 33.55 MB
  constexpr size_t OFF_WPJ  = OFF_WFC  + (size_t)NEXP * INTR * HID * 2;  // 33.55 MB
  constexpr size_t OFF_WFS  = OFF_WPJ  + (size_t)NEXP * HID * INTR * 2;  // 2.10 MB
  constexpr size_t OFF_WPS  = OFF_WFS  + (size_t)SINT * HID * 2;  // 2.10 MB
  constexpr size_t OFF_H    = OFF_WPS  + (size_t)HID * SINT * 2;  // 71.30 MB
  constexpr size_t OFF_HS   = OFF_H    + (size_t)MAXSLOT * INTR * 2;  // 16.78 MB
  constexpr size_t OFF_Y    = OFF_HS   + (size_t)TOKS * SINT * 2;  // 35.65 MB
  constexpr size_t OFF_YS   = OFF_Y    + (size_t)MAXSLOT * HID * 2;  // 16.78 MB
  constexpr size_t OFF_CNT  = OFF_YS   + (size_t)TOKS * HID * 2;
  constexpr size_t OFF_OFFS = OFF_CNT  + 32;
  constexpr size_t OFF_RECE = OFF_OFFS + 256;   // offs[0..8] + tb0[16..24] + tb1[32..40]
  constexpr size_t OFF_RECP = OFF_RECE + (size_t)TOKS * 4;
  constexpr size_t OFF_RECG = OFF_RECP + (size_t)TOKS * 4;
  constexpr size_t OFF_TOK  = OFF_RECG + (size_t)TOKS * 8;
  // total ~229 MB

  unsigned short* xb   = (unsigned short*)(ws + OFF_XB);
  unsigned short* wfcb = (unsigned short*)(ws + OFF_WFC);
  unsigned short* wpjb = (unsigned short*)(ws + OFF_WPJ);
  unsigned short* wfsb = (unsigned short*)(ws + OFF_WFS);
  unsigned short* wpsb = (unsigned short*)(ws + OFF_WPS);
  unsigned short* h    = (unsigned short*)(ws + OFF_H);
  unsigned short* hs   = (unsigned short*)(ws + OFF_HS);
  unsigned short* Y    = (unsigned short*)(ws + OFF_Y);
  unsigned short* Ys   = (unsigned short*)(ws + OFF_YS);
  int*    cnt   = (int*)(ws + OFF_CNT);
  int*    offs  = (int*)(ws + OFF_OFFS);
  int*    rec_e = (int*)(ws + OFF_RECE);
  int*    rec_p = (int*)(ws + OFF_RECP);
  float2* rec_g = (float2*)(ws + OFF_RECG);
  int*    tok   = (int*)(ws + OFF_TOK);

  hipMemsetAsync(cnt, 0, NEXP * sizeof(int), stream);

  // one fused convert for all 4 weight tensors
  k_f2bf_all<<<2048, 256, 0, stream>>>(
      wfc, wfcb, NEXP * INTR * HID / 4,
      wpj, wpjb, NEXP * HID * INTR / 4,
      wfs, wfsb, SINT * HID / 4,
      wps, wpsb, HID * SINT / 4);

  k_router<<<TOKS / 4, 256, 0, stream>>>(x, wg, xb, rec_e, rec_g);
  k_count<<<TOKS / 256, 256, 0, stream>>>(rec_e, rec_p, cnt);
  k_scan<<<1, 64, 0, stream>>>(cnt, offs);
  k_assign<<<TOKS / 256, 256, 0, stream>>>(rec_e, rec_p, offs, tok);

  // worst-case flattened grids (sum ceil(c_e/128) <= 136); tail blocks exit on total
  constexpr int GRID0 = 136 * (INTR / 128);        // 2176
  constexpr int GRID1 = 136 * (HID / 128);         // 1088
  constexpr int GRID2 = (TOKS / 128) * (SINT / 128);  // 512
  constexpr int GRID3 = (TOKS / 128) * (HID / 128);   // 512

  // expert fc: gathered A, N=2048, K=1024 -> h (gelu)
  k_gemm2<0><<<GRID0, 256, 0, stream>>>(xb, wfcb, h, cnt, offs, tok, HID, INTR);
  // shared fc: M=8192, N=1024, K=1024 -> hs (gelu)
  k_gemm2<2><<<GRID2, 256, 0, stream>>>(xb, wfsb, hs, cnt, offs, tok, HID, SINT);
  // expert proj: N=1024, K=2048 -> Y (raw bf16, per-slot)
  k_gemm2<1><<<GRID1, 256, 0, stream>>>(h, wpjb, Y, cnt, offs, tok, INTR, HID);
  // shared proj: N=1024, K=1024 -> Ys (raw bf16)
  k_gemm2<3><<<GRID3, 256, 0, stream>>>(hs, wpsb, Ys, cnt, offs, tok, SINT, HID);

  // final combine: out[t] = g0*Y[s0] + g1*Y[s1] + Ys[t]
  k_combine<<<TOKS, 256, 0, stream>>>(Y, Ys, rec_e, rec_p, rec_g, offs, out);
}

// Round 5
// 431.956 us; speedup vs baseline: 1.0926x; 1.0926x over previous
//
#include <hip/hip_runtime.h>
#include <cstdint>
#include <cstdio>

#define DEVI __device__ __forceinline__

constexpr int TOKS = 8192;
constexpr int HID  = 1024;
constexpr int INTR = 2048;
constexpr int SINT = 1024;
constexpr int NEXP = 8;
constexpr int MAXSLOT = 17408;   // 16384 assignments + 8*127 padding, rounded up

typedef __bf16 bf16x8 __attribute__((ext_vector_type(8)));
typedef float  f32x4  __attribute__((ext_vector_type(4)));

DEVI unsigned short f2bf(float f) {
  unsigned int u = __float_as_uint(f);
  u += 0x7FFFu + ((u >> 16) & 1u);   // round-to-nearest-even
  return (unsigned short)(u >> 16);
}

DEVI float bf2f(unsigned short h) {
  return __uint_as_float((unsigned int)h << 16);
}

// async global->LDS, 16B per lane. LDS dest = wave-uniform base + lane*16
// (our per-thread tid*16B dest is exactly that); global addr per-lane (gather OK).
DEVI void gl_lds16(const unsigned short* g, unsigned short* l) {
  __attribute__((address_space(1))) uint32_t* gp =
      (__attribute__((address_space(1))) uint32_t*)(uintptr_t)g;
  __attribute__((address_space(3))) uint32_t* lp =
      (__attribute__((address_space(3))) uint32_t*)(uint32_t)(uintptr_t)l;
  __builtin_amdgcn_global_load_lds(gp, lp, 16, 0, 0);
}

// exact-gelu via Abramowitz-Stegun 7.1.26 erf (|err| <= 1.5e-7), ~14 VALU ops.
DEVI float gelu_fast(float x) {
  const float z = fabsf(x) * 0.70710678118654752f;
  const float t = __builtin_amdgcn_rcpf(1.0f + 0.3275911f * z);
  float p = 1.061405429f;
  p = p * t - 1.453152027f;
  p = p * t + 1.421413741f;
  p = p * t - 0.284496736f;
  p = p * t + 0.254829592f;
  const float e = __builtin_amdgcn_exp2f(-z * z * 1.4426950408889634f);  // exp(-z^2)
  float erfz = 1.0f - p * t * e;     // erf(|z|)
  erfz = copysignf(erfz, x);
  return 0.5f * x * (1.0f + erfz);
}

// bijective XCD-chunked remap (m204): XCD k (= bid%8 dispatch heuristic) owns a
// contiguous chunk of the active tile space -> per-XCD L2 keeps one B-panel hot.
DEVI int xcd_chunk_map(int bid, int total) {
  const int q = total >> 3, r = total & 7;
  const int x = bid & 7, i = bid >> 3;
  return (x < r ? x * (q + 1) : r * (q + 1) + (x - r) * q) + i;
}

// ---------------- fused fp32 -> bf16 convert over 4 weight arrays ----------------
__global__ void k_f2bf_all(const float* __restrict__ s0, unsigned short* __restrict__ d0, int n0,
                           const float* __restrict__ s1, unsigned short* __restrict__ d1, int n1,
                           const float* __restrict__ s2, unsigned short* __restrict__ d2, int n2,
                           const float* __restrict__ s3, unsigned short* __restrict__ d3, int n3) {
  const int ntot = n0 + n1 + n2 + n3;
  int i = blockIdx.x * blockDim.x + threadIdx.x;
  const int stride = gridDim.x * blockDim.x;
  for (; i < ntot; i += stride) {
    int j = i;
    const float* s; unsigned short* d;
    if (j < n0) { s = s0; d = d0; }
    else if ((j -= n0) < n1) { s = s1; d = d1; }
    else if ((j -= n1) < n2) { s = s2; d = d2; }
    else { j -= n2; s = s3; d = d3; }
    float4 v = ((const float4*)s)[j];
    ushort4 o;
    o.x = f2bf(v.x); o.y = f2bf(v.y); o.z = f2bf(v.z); o.w = f2bf(v.w);
    ((ushort4*)d)[j] = o;
  }
}

// ---------------- router: fp32 logits, top-2, softmax. NO ATOMICS. ----------------
__global__ __launch_bounds__(256) void k_router(
    const float* __restrict__ x, const float* __restrict__ wg,
    unsigned short* __restrict__ xb,
    int* __restrict__ rec_e, float2* __restrict__ rec_g) {
  const int wave = threadIdx.x >> 6;
  const int lane = threadIdx.x & 63;
  const int t = blockIdx.x * 4 + wave;

  float4 xv[4];
  const float4* x4 = (const float4*)(x + (size_t)t * HID);
#pragma unroll
  for (int j = 0; j < 4; ++j) xv[j] = x4[j * 64 + lane];

  // emit bf16 copy of x
  ushort4* xb4 = (ushort4*)(xb + (size_t)t * HID);
#pragma unroll
  for (int j = 0; j < 4; ++j) {
    float4 v = xv[j];
    ushort4 o; o.x = f2bf(v.x); o.y = f2bf(v.y); o.z = f2bf(v.z); o.w = f2bf(v.w);
    xb4[j * 64 + lane] = o;
  }

  float lg[NEXP];
#pragma unroll
  for (int e = 0; e < NEXP; ++e) {
    const float4* w4 = (const float4*)(wg + (size_t)e * HID);
    float s = 0.f;
#pragma unroll
    for (int j = 0; j < 4; ++j) {
      float4 a = xv[j], b = w4[j * 64 + lane];
      s += a.x * b.x + a.y * b.y + a.z * b.z + a.w * b.w;
    }
    lg[e] = s;
  }
#pragma unroll
  for (int e = 0; e < NEXP; ++e)
#pragma unroll
    for (int off = 32; off > 0; off >>= 1) lg[e] += __shfl_xor(lg[e], off);

  if (lane == 0) {
    int b0 = 0; float v0 = lg[0];
    for (int e = 1; e < NEXP; ++e) if (lg[e] > v0) { v0 = lg[e]; b0 = e; }
    int b1 = -1; float v1 = -1e30f;
    for (int e = 0; e < NEXP; ++e) if (e != b0 && lg[e] > v1) { v1 = lg[e]; b1 = e; }
    const float d = expf(v1 - v0);
    const float g0 = 1.f / (1.f + d);
    const float g1 = d / (1.f + d);
    rec_e[t] = b0 | (b1 << 16);
    rec_g[t] = make_float2(g0, g1);
  }
}

// ---------------- count: hierarchical rank-within-expert (LDS hist + 8 global atomics/block) ----------------
__global__ __launch_bounds__(256) void k_count(
    const int* __restrict__ rec_e, int* __restrict__ rec_p, int* __restrict__ cnt) {
  __shared__ int hist[NEXP];
  __shared__ int base[NEXP];
  const int t = blockIdx.x * 256 + threadIdx.x;
  if (threadIdx.x < NEXP) hist[threadIdx.x] = 0;
  __syncthreads();
  const int ee = rec_e[t];
  const int e0 = ee & 0xffff, e1 = ee >> 16;
  const int r0 = atomicAdd(&hist[e0], 1);   // LDS atomic: intra-block rank
  const int r1 = atomicAdd(&hist[e1], 1);
  __syncthreads();
  if (threadIdx.x < NEXP)
    base[threadIdx.x] = atomicAdd(&cnt[threadIdx.x], hist[threadIdx.x]);  // 8 global atomics/block
  __syncthreads();
  rec_p[t] = (base[e0] + r0) | ((base[e1] + r1) << 16);
}

// ---------------- scan: 128-padded offsets + per-expert tile tables ----------------
// offs[0..8]  : 128-padded slot offsets
// offs[16..24]: tb0 cumulative tile count for expert-fc   (m-tiles * INTR/128)
// offs[32..40]: tb1 cumulative tile count for expert-proj (m-tiles * HID/128)
__global__ void k_scan(const int* __restrict__ cnt, int* __restrict__ offs) {
  if (threadIdx.x == 0 && blockIdx.x == 0) {
    int* tb0 = offs + 16;
    int* tb1 = offs + 32;
    int o = 0, t0 = 0, t1 = 0;
    tb0[0] = 0; tb1[0] = 0;
    for (int e = 0; e < NEXP; ++e) {
      offs[e] = o;
      const int mt = (cnt[e] + 127) >> 7;
      o += mt << 7;
      t0 += mt * (INTR / 128);
      t1 += mt * (HID / 128);
      tb0[e + 1] = t0;
      tb1[e + 1] = t1;
    }
    offs[NEXP] = o;
  }
}

// ---------------- assign: fill slot arrays ----------------
__global__ void k_assign(const int* __restrict__ rec_e, const int* __restrict__ rec_p,
                         const int* __restrict__ offs, int* __restrict__ tok) {
  const int t = blockIdx.x * 256 + threadIdx.x;
  if (t >= TOKS) return;
  const int ee = rec_e[t], pp = rec_p[t];
  const int s0 = offs[ee & 0xffff] + (pp & 0xffff);
  const int s1 = offs[ee >> 16] + (pp >> 16);
  tok[s0] = t;
  tok[s1] = t;
}

// ---------------- fused GEMM pair: C[m,n] = sum_k A[m,k]*B[n,k]  (B row-major [N,K]) ------
// Round-3-verified inner loop: 128x128 tile, BK=64, 256 thr = 4 waves (2Mx2N), 64KB LDS
// double-buffer -> 2 blocks/CU. 2-phase pipeline: stage(next) issued BEFORE compute(cur);
// one __syncthreads per K-step. 8-chunk XOR swizzle on BOTH staging source and ds_read
// addr (verified 0 conflicts). Flattened 1-D grid with XCD-chunked remap.
// NEW vs round 3: expert tiles [0, expTotal) and shared tiles [expTotal, total) run in ONE
// launch (independent work, same shape) -> 2 launches instead of 4, shared work packs the
// expert GEMM's scheduling tail.
// PHASE 0 (FC, gelu): expert {A=xb gathered via tok, B=wfc, out=h, N=2048,K=1024}
//                     shared {A=xb, B=wfs, out=hs, N=1024,K=1024}
// PHASE 1 (PROJ,raw): expert {A=h (slot rows), B=wpj, out=Y, N=1024,K=2048}
//                     shared {A=hs, B=wps, out=Ys, N=1024,K=1024}
template <int PHASE>
__global__ __launch_bounds__(256, 2) void k_gemmF(
    const unsigned short* __restrict__ Ae,
    const unsigned short* __restrict__ Be,
    unsigned short* __restrict__ He,
    const unsigned short* __restrict__ Ash,
    const unsigned short* __restrict__ Bsh,
    unsigned short* __restrict__ Hsh,
    const int* __restrict__ cnt,
    const int* __restrict__ offs,
    const int* __restrict__ tok) {
  constexpr int SH_TILES = (TOKS / 128) * 8;   // shared N=1024 -> 8 n-tiles; 512 tiles

  const int* tb = offs + ((PHASE == 0) ? 16 : 32);
  const int expTotal = tb[8];
  const int total = expTotal + SH_TILES;
  int bid = blockIdx.x;
  if (bid >= total) return;                    // tail overflow blocks exit fast
  bid = xcd_chunk_map(bid, total);

  const unsigned short *A, *B;
  unsigned short* Hout;
  int count, gOff = 0, m0, n0, K, N;
  bool gather = false;
  if (bid < expTotal) {
    constexpr int NT_SHIFT = (PHASE == 0) ? 4 : 3;   // log2(N/128)
    int e = 0;
    while (bid >= tb[e + 1]) ++e;              // <=8 scalar iters
    const int local = bid - tb[e];
    count = cnt[e];
    const int off = offs[e];
    m0 = (local >> NT_SHIFT) << 7;             // nt-fastest within expert
    n0 = (local & ((1 << NT_SHIFT) - 1)) << 7;
    K = (PHASE == 0) ? HID : INTR;
    N = (PHASE == 0) ? INTR : HID;
    if (PHASE == 0) { A = Ae; gather = true; gOff = off; }   // gather x rows via tok
    else            { A = Ae + (size_t)off * K; }            // slot rows of h
    B = Be + (size_t)e * (size_t)N * K;
    Hout = He + (size_t)off * N;
  } else {
    const int local = bid - expTotal;
    count = TOKS;
    m0 = (local >> 3) << 7;
    n0 = (local & 7) << 7;
    K = (PHASE == 0) ? HID : SINT;
    N = (PHASE == 0) ? SINT : HID;
    A = Ash; B = Bsh; Hout = Hsh;
  }

  __shared__ alignas(16) unsigned short As[2][128 * 64];   // 32KB
  __shared__ alignas(16) unsigned short Bs[2][128 * 64];   // 32KB

  const int tid = threadIdx.x;

  // ---- staging: 4 rounds of 32 rows each; source chunk pre-swizzled, LDS dest linear ----
  const int srow = tid >> 3;                  // 0..31
  const int schunk = tid & 7;                 // 16B chunk within 128B row
  const unsigned short* gA[4];
  const unsigned short* gB[4];
#pragma unroll
  for (int r = 0; r < 4; ++r) {
    const int gr = r * 32 + srow;             // row within tile (0..127)
    int mr = m0 + gr; if (mr > count - 1) mr = count - 1;   // clamp tail rows
    const int row = gather ? tok[gOff + mr] : mr;
    const int sc = ((schunk ^ (gr & 7)) & 7) * 8;
    gA[r] = A + (size_t)row * (size_t)K + sc;
    gB[r] = B + (size_t)(n0 + gr) * (size_t)K + sc;
  }

  // ---- ds_read byte offsets (swizzled); subtile s flips bit 6 ----
  const int wid = tid >> 6;
  const int lane = tid & 63;
  const int wr = wid >> 1;                    // 0..1
  const int wc = wid & 1;                     // 0..1
  const int fm = lane & 15;
  const int fq = lane >> 4;
  int aOff[4], bOff[4];
#pragma unroll
  for (int i = 0; i < 4; ++i) {
    const int row = wr * 64 + i * 16 + fm;
    aOff[i] = row * 128 + ((fq ^ (row & 7)) * 16);
  }
#pragma unroll
  for (int j = 0; j < 4; ++j) {
    const int row = wc * 64 + j * 16 + fm;
    bOff[j] = row * 128 + ((fq ^ (row & 7)) * 16);
  }

  auto stage = [&](int buf, int k0) {
#pragma unroll
    for (int r = 0; r < 4; ++r)
      gl_lds16(gA[r] + k0, &As[buf][r * 2048 + tid * 8]);
#pragma unroll
    for (int r = 0; r < 4; ++r)
      gl_lds16(gB[r] + k0, &Bs[buf][r * 2048 + tid * 8]);
  };

  f32x4 acc[4][4] = {};

  stage(0, 0);
  __syncthreads();

  int cur = 0;
  for (int k0 = 0; k0 < K; k0 += 64) {
    const bool more = (k0 + 64 < K);
    if (more) stage(cur ^ 1, k0 + 64);        // issue next-tile loads FIRST

    const char* aBase = (const char*)&As[cur][0];
    const char* bBase = (const char*)&Bs[cur][0];
    __builtin_amdgcn_s_setprio(1);
#pragma unroll
    for (int s = 0; s < 2; ++s) {             // two K=32 subtiles
      bf16x8 af[4], bfr[4];
#pragma unroll
      for (int i = 0; i < 4; ++i)
        af[i] = *(const bf16x8*)(aBase + (aOff[i] ^ (s << 6)));
#pragma unroll
      for (int j = 0; j < 4; ++j)
        bfr[j] = *(const bf16x8*)(bBase + (bOff[j] ^ (s << 6)));
#pragma unroll
      for (int i = 0; i < 4; ++i)
#pragma unroll
        for (int j = 0; j < 4; ++j)
          acc[i][j] = __builtin_amdgcn_mfma_f32_16x16x32_bf16(af[i], bfr[j], acc[i][j], 0, 0, 0);
    }
    __builtin_amdgcn_s_setprio(0);

    if (more) { __syncthreads(); cur ^= 1; }  // one barrier (w/ vmcnt drain) per K-step
  }

  // ---- epilogue: C/D row = fq*4 + reg, col = lane&15 ----
  constexpr bool GELU = (PHASE == 0);
#pragma unroll
  for (int i = 0; i < 4; ++i) {
#pragma unroll
    for (int rr = 0; rr < 4; ++rr) {
      const int m = m0 + wr * 64 + i * 16 + fq * 4 + rr;
      if (m < count) {                        // guard pad rows
        unsigned short* orow = Hout + (size_t)m * N + (n0 + wc * 64 + fm);
#pragma unroll
        for (int j = 0; j < 4; ++j) {
          const float v = acc[i][j][rr];
          orow[j * 16] = f2bf(GELU ? gelu_fast(v) : v);
        }
      }
    }
  }
}

// ---------------- combine: out[t] = g0*Y[s0] + g1*Y[s1] + Ys[t] ----------------
__global__ __launch_bounds__(256) void k_combine(
    const unsigned short* __restrict__ Y,   // [MAXSLOT, HID] bf16
    const unsigned short* __restrict__ Ys,  // [TOKS, HID] bf16
    const int* __restrict__ rec_e, const int* __restrict__ rec_p,
    const float2* __restrict__ rec_g, const int* __restrict__ offs,
    float* __restrict__ out) {
  const int t = blockIdx.x;
  const int ee = rec_e[t], pp = rec_p[t];
  const float2 g = rec_g[t];
  const int s0 = offs[ee & 0xffff] + (pp & 0xffff);
  const int s1 = offs[ee >> 16] + (pp >> 16);
  const int c = threadIdx.x * 4;
  ushort4 a = *(const ushort4*)&Y[(size_t)s0 * HID + c];
  ushort4 b = *(const ushort4*)&Y[(size_t)s1 * HID + c];
  ushort4 s = *(const ushort4*)&Ys[(size_t)t * HID + c];
  float4 o;
  o.x = g.x * bf2f(a.x) + g.y * bf2f(b.x) + bf2f(s.x);
  o.y = g.x * bf2f(a.y) + g.y * bf2f(b.y) + bf2f(s.y);
  o.z = g.x * bf2f(a.z) + g.y * bf2f(b.z) + bf2f(s.z);
  o.w = g.x * bf2f(a.w) + g.y * bf2f(b.w) + bf2f(s.w);
  *(float4*)&out[(size_t)t * HID + c] = o;
}

extern "C" void kernel_launch(void* const* d_in, const int* in_sizes, int n_in,
                              void* d_out, int out_size, void* d_ws, size_t ws_size,
                              hipStream_t stream) {
  const float* x   = (const float*)d_in[0];
  const float* wg  = (const float*)d_in[1];
  const float* wfc = (const float*)d_in[2];
  const float* wpj = (const float*)d_in[3];
  const float* wfs = (const float*)d_in[4];
  const float* wps = (const float*)d_in[5];
  float* out = (float*)d_out;
  char* ws = (char*)d_ws;

  // workspace layout (bytes)
  constexpr size_t OFF_XB   = 0;                                  // 16.78 MB
  constexpr size_t OFF_WFC  = OFF_XB   + (size_t)TOKS * HID * 2;  // 33.55 MB
  constexpr size_t OFF_WPJ  = OFF_WFC  + (size_t)NEXP * INTR * HID * 2;  // 33.55 MB
  constexpr size_t OFF_WFS  = OFF_WPJ  + (size_t)NEXP * HID * INTR * 2;  // 2.10 MB
  constexpr size_t OFF_WPS  = OFF_WFS  + (size_t)SINT * HID * 2;  // 2.10 MB
  constexpr size_t OFF_H    = OFF_WPS  + (size_t)HID * SINT * 2;  // 71.30 MB
  constexpr size_t OFF_HS   = OFF_H    + (size_t)MAXSLOT * INTR * 2;  // 16.78 MB
  constexpr size_t OFF_Y    = OFF_HS   + (size_t)TOKS * SINT * 2;  // 35.65 MB
  constexpr size_t OFF_YS   = OFF_Y    + (size_t)MAXSLOT * HID * 2;  // 16.78 MB
  constexpr size_t OFF_CNT  = OFF_YS   + (size_t)TOKS * HID * 2;
  constexpr size_t OFF_OFFS = OFF_CNT  + 32;
  constexpr size_t OFF_RECE = OFF_OFFS + 256;   // offs[0..8] + tb0[16..24] + tb1[32..40]
  constexpr size_t OFF_RECP = OFF_RECE + (size_t)TOKS * 4;
  constexpr size_t OFF_RECG = OFF_RECP + (size_t)TOKS * 4;
  constexpr size_t OFF_TOK  = OFF_RECG + (size_t)TOKS * 8;
  // total ~229 MB

  unsigned short* xb   = (unsigned short*)(ws + OFF_XB);
  unsigned short* wfcb = (unsigned short*)(ws + OFF_WFC);
  unsigned short* wpjb = (unsigned short*)(ws + OFF_WPJ);
  unsigned short* wfsb = (unsigned short*)(ws + OFF_WFS);
  unsigned short* wpsb = (unsigned short*)(ws + OFF_WPS);
  unsigned short* h    = (unsigned short*)(ws + OFF_H);
  unsigned short* hs   = (unsigned short*)(ws + OFF_HS);
  unsigned short* Y    = (unsigned short*)(ws + OFF_Y);
  unsigned short* Ys   = (unsigned short*)(ws + OFF_YS);
  int*    cnt   = (int*)(ws + OFF_CNT);
  int*    offs  = (int*)(ws + OFF_OFFS);
  int*    rec_e = (int*)(ws + OFF_RECE);
  int*    rec_p = (int*)(ws + OFF_RECP);
  float2* rec_g = (float2*)(ws + OFF_RECG);
  int*    tok   = (int*)(ws + OFF_TOK);

  hipMemsetAsync(cnt, 0, NEXP * sizeof(int), stream);

  // one fused convert for all 4 weight tensors
  k_f2bf_all<<<2048, 256, 0, stream>>>(
      wfc, wfcb, NEXP * INTR * HID / 4,
      wpj, wpjb, NEXP * HID * INTR / 4,
      wfs, wfsb, SINT * HID / 4,
      wps, wpsb, HID * SINT / 4);

  k_router<<<TOKS / 4, 256, 0, stream>>>(x, wg, xb, rec_e, rec_g);
  k_count<<<TOKS / 256, 256, 0, stream>>>(rec_e, rec_p, cnt);
  k_scan<<<1, 64, 0, stream>>>(cnt, offs);
  k_assign<<<TOKS / 256, 256, 0, stream>>>(rec_e, rec_p, offs, tok);

  // worst-case flattened grids: expert tiles (sum ceil(c_e/128) <= 136) + 512 shared tiles
  constexpr int GRID_FC = 136 * (INTR / 128) + (TOKS / 128) * 8;   // 2176 + 512 = 2688
  constexpr int GRID_PJ = 136 * (HID  / 128) + (TOKS / 128) * 8;   // 1088 + 512 = 1600

  // fused FC: expert fc (gather, N=2048,K=1024 -> h) + shared fc (N=1024,K=1024 -> hs)
  k_gemmF<0><<<GRID_FC, 256, 0, stream>>>(xb, wfcb, h, xb, wfsb, hs, cnt, offs, tok);
  // fused PROJ: expert proj (N=1024,K=2048 -> Y) + shared proj (N=1024,K=1024 -> Ys)
  k_gemmF<1><<<GRID_PJ, 256, 0, stream>>>(h, wpjb, Y, hs, wpsb, Ys, cnt, offs, tok);

  // final combine: out[t] = g0*Y[s0] + g1*Y[s1] + Ys[t]
  k_combine<<<TOKS, 256, 0, stream>>>(Y, Ys, rec_e, rec_p, rec_g, offs, out);
}